// Round 11
// baseline (313.732 us; speedup 1.0000x reference)
//
#include <hip/hip_runtime.h>

#define NQ 1024
#define NO 2048
#define LAT 128
#define CHUNK 16
#define NCHUNK (NO / CHUNK)          // 128
#define LDSTR 132   // padded LDS row stride (floats)
#define LOG2E 1.4426950408889634f
#define NEG_BIG -3.0e38f
#define MASK_THRESH -1.0e37f
#define PART_STRIDE 136   // 4 m + 4 lsum + 128 acc (floats per (slot,q))
#define SY_MAX 32

// workspace layout (float indices)
#define WS_DO   0                    // d_o [NO*LAT]
#define WS_CNT  (NO*LAT)             // 64 int counters (one per x-block)
#define WS_PART (NO*LAT + 64)        // partials [SY][NQ][PART_STRIDE]

// ---------------------------------------------------------------------------
// value path: h_obs <- LayerNorm(h_obs) @ Wv + bv (in place), PLUS
// d_o precompute (d_o = pos_o · (W1[3:6]-W1[6:9])) into ws, PLUS zeroing the
// 64 split-K counters (stream order guarantees all done before gano_main).
// ---------------------------------------------------------------------------
__global__ __launch_bounds__(256) void gano_value(
    const float* __restrict__ ln_g,
    const float* __restrict__ ln_b,
    const float* __restrict__ Wv,
    const float* __restrict__ bv,
    const float* __restrict__ W1,
    const float* __restrict__ pos_obs,
    float* __restrict__ h,
    float* __restrict__ wsf)         // may be null (tiny-ws fallback)
{
    __shared__ float hn[2][LAT];
    __shared__ float red[2][4];
    const int t = threadIdx.x;
    const int o = t >> 7;           // obs within block (0..1)
    const int d = t & 127;          // dim
    const int ob = blockIdx.x * 2 + o;

    const float x = h[(size_t)ob*LAT + d];
    float s1 = x, s2 = x*x;
#pragma unroll
    for (int off = 32; off >= 1; off >>= 1) {
        s1 += __shfl_xor(s1, off);
        s2 += __shfl_xor(s2, off);
    }
    const int wv = (t >> 6) & 1;
    if ((t & 63) == 0) { red[o][wv*2] = s1; red[o][wv*2+1] = s2; }

    // d_o while the barrier settles
    if (wsf) {
        const float p0 = pos_obs[ob*3+0];
        const float p1 = pos_obs[ob*3+1];
        const float p2 = pos_obs[ob*3+2];
        float ds =      p0 * (W1[3*LAT + d] - W1[6*LAT + d]);
        ds = fmaf(p1,        W1[4*LAT + d] - W1[7*LAT + d], ds);
        ds = fmaf(p2,        W1[5*LAT + d] - W1[8*LAT + d], ds);
        wsf[WS_DO + (size_t)ob*LAT + d] = ds;
        if (blockIdx.x == 0 && t < 64) ((int*)(wsf + WS_CNT))[t] = 0;
    }
    __syncthreads();
    const float S1 = red[o][0] + red[o][2];
    const float S2 = red[o][1] + red[o][3];
    const float mean = S1 * (1.0f/LAT);
    const float var  = S2 * (1.0f/LAT) - mean*mean;
    const float rstd = rsqrtf(var + 1e-5f);
    hn[o][d] = (x - mean) * rstd * ln_g[d] + ln_b[d];
    __syncthreads();

    float a0 = bv[d], a1 = 0.f, a2 = 0.f, a3 = 0.f;
    const float* wc = Wv + d;
    const float* hh = hn[o];
#pragma unroll 8
    for (int kk = 0; kk < 32; ++kk) {
        a0 = fmaf(hh[kk],      wc[(size_t)(kk)*LAT],      a0);
        a1 = fmaf(hh[kk + 32], wc[(size_t)(kk + 32)*LAT], a1);
        a2 = fmaf(hh[kk + 64], wc[(size_t)(kk + 64)*LAT], a2);
        a3 = fmaf(hh[kk + 96], wc[(size_t)(kk + 96)*LAT], a3);
    }
    h[(size_t)ob*LAT + d] = (a0 + a1) + (a2 + a3);
}

// ---------------------------------------------------------------------------
// main, two-phase per chunk — NO per-chunk staging (R10 lesson: ILP via
// bigger tiles costs VGPR-occupancy; instead DELETE the staging work):
//  d_o precomputed in ws (L2-resident; 1 global b128/j), c_q in padded LDS,
//  W1[9]/W2 uniform s_loads, pos/batch read per-thread (L1 broadcast).
//  Phase 2 identical to R9. LDS ~13 KB -> residency VGPR-bound only.
// Split-K combine FUSED: partials -> fence -> atomicAdd(counter[x]); the
// last arriving block reduces and writes out (one launch removed).
// Plain __launch_bounds__(256): min-waves arg caps VGPR at 256/w (R7 spill).
// ---------------------------------------------------------------------------
__global__ __launch_bounds__(256) void gano_main(
    const float* __restrict__ v,          // h_obs buffer, now holding v
    const float* __restrict__ pos_obs,
    const float* __restrict__ pos_query,
    const int* __restrict__ obs_batch,
    const int* __restrict__ query_batch,
    const float* __restrict__ W1,
    const float* __restrict__ b1,
    const float* __restrict__ W2,
    const float* __restrict__ b2,
    float* __restrict__ ws,               // null in tiny-ws fallback
    float* __restrict__ out,
    int SY)
{
    __shared__ __align__(16) float lcq[16*LDSTR];     // c_q, padded  8.4 KB
    __shared__ __align__(16) float lgt[16*4*CHUNK];   // logits         4 KB
    __shared__ int lastflag;

    const int tid = threadIdx.x;
    const int i  = tid & 15;        // phase1: oc ; phase2: dim-slice
    const int qi = tid >> 4;        // query within block
    const int q  = blockIdx.x * 16 + qi;
    const int d0 = i * 8;           // phase-2 dims
    const int hstar = i >> 2;       // phase-2 head

    // ---- block-init: c_q into LDS (padded rows) ----
#pragma unroll
    for (int t2 = 0; t2 < 2; ++t2) {
        const int idx = tid + t2*256;
        const int row = idx >> 5;            // query 0..15
        const int g   = idx & 31;            // float4 group
        const int dd4 = g * 4;
        const int qq  = blockIdx.x * 16 + row;
        const float px = pos_query[qq*3+0];
        const float py = pos_query[qq*3+1];
        const float pz = pos_query[qq*3+2];
        float4 c = *(const float4*)(b1 + dd4);
        const float4 wx0 = *(const float4*)(W1 + 0*LAT + dd4);
        const float4 wx6 = *(const float4*)(W1 + 6*LAT + dd4);
        const float4 wy0 = *(const float4*)(W1 + 1*LAT + dd4);
        const float4 wy6 = *(const float4*)(W1 + 7*LAT + dd4);
        const float4 wz0 = *(const float4*)(W1 + 2*LAT + dd4);
        const float4 wz6 = *(const float4*)(W1 + 8*LAT + dd4);
        c.x = fmaf(px, wx0.x+wx6.x, fmaf(py, wy0.x+wy6.x, fmaf(pz, wz0.x+wz6.x, c.x)));
        c.y = fmaf(px, wx0.y+wx6.y, fmaf(py, wy0.y+wy6.y, fmaf(pz, wz0.y+wz6.y, c.y)));
        c.z = fmaf(px, wx0.z+wx6.z, fmaf(py, wy0.z+wy6.z, fmaf(pz, wz0.z+wz6.z, c.z)));
        c.w = fmaf(px, wx0.w+wx6.w, fmaf(py, wy0.w+wy6.w, fmaf(pz, wz0.w+wz6.w, c.w)));
        *(float4*)(lcq + row*LDSTR + dd4) = c;
    }

    const float pqx = pos_query[q*3+0];
    const float pqy = pos_query[q*3+1];
    const float pqz = pos_query[q*3+2];
    const int   qb  = query_batch[q];
    const float b2l0 = b2[0]*LOG2E, b2l1 = b2[1]*LOG2E;
    const float b2l2 = b2[2]*LOG2E, b2l3 = b2[3]*LOG2E;

    float4 accA = make_float4(0.f,0.f,0.f,0.f);
    float4 accB = make_float4(0.f,0.f,0.f,0.f);
    float m = NEG_BIG, lsum = 0.f;

    const float* dob = ws ? (ws + WS_DO) : nullptr;

    for (int cb = blockIdx.y; cb < NCHUNK; cb += SY) {
        const int o0 = cb * CHUNK;
        __syncthreads();   // prior phase-2 lgt reads done; lcq ready (1st)

        // ---- phase 1: one full logit per thread ----
        {
            const int obs = o0 + i;
            const float px = pos_obs[obs*3+0];
            const float py = pos_obs[obs*3+1];
            const float pz = pos_obs[obs*3+2];
            const float dx = pqx - px, dy = pqy - py, dz = pqz - pz;
            const float dist = sqrtf(dx*dx + dy*dy + dz*dz);
            const int mb = (obs_batch[obs] == qb);

            float lg0 = 0.f, lg1 = 0.f, lg2 = 0.f, lg3 = 0.f;
            const float* lcr = lcq + qi*LDSTR;
            if (dob) {
                const float* dr = dob + (size_t)obs*LAT;
#pragma unroll 4
                for (int j = 0; j < 32; ++j) {
                    const float4 dd = *(const float4*)(dr + j*4);      // global b128 (L2)
                    const float4 cc = *(const float4*)(lcr + j*4);     // ds b128 imm
                    const float4 wd = *(const float4*)(W1 + 9*LAT + j*4);  // s_load
                    const float4 w2a = *(const float4*)(W2 + (j*4+0)*4);
                    const float4 w2b = *(const float4*)(W2 + (j*4+1)*4);
                    const float4 w2c = *(const float4*)(W2 + (j*4+2)*4);
                    const float4 w2d = *(const float4*)(W2 + (j*4+3)*4);
                    const float h0 = fmaxf(fmaf(wd.x, dist, cc.x + dd.x), 0.f);
                    const float h1 = fmaxf(fmaf(wd.y, dist, cc.y + dd.y), 0.f);
                    const float h2 = fmaxf(fmaf(wd.z, dist, cc.z + dd.z), 0.f);
                    const float h3 = fmaxf(fmaf(wd.w, dist, cc.w + dd.w), 0.f);
                    lg0 = fmaf(h0, w2a.x, lg0); lg1 = fmaf(h0, w2a.y, lg1);
                    lg2 = fmaf(h0, w2a.z, lg2); lg3 = fmaf(h0, w2a.w, lg3);
                    lg0 = fmaf(h1, w2b.x, lg0); lg1 = fmaf(h1, w2b.y, lg1);
                    lg2 = fmaf(h1, w2b.z, lg2); lg3 = fmaf(h1, w2b.w, lg3);
                    lg0 = fmaf(h2, w2c.x, lg0); lg1 = fmaf(h2, w2c.y, lg1);
                    lg2 = fmaf(h2, w2c.z, lg2); lg3 = fmaf(h2, w2c.w, lg3);
                    lg0 = fmaf(h3, w2d.x, lg0); lg1 = fmaf(h3, w2d.y, lg1);
                    lg2 = fmaf(h3, w2d.z, lg2); lg3 = fmaf(h3, w2d.w, lg3);
                }
            } else {   // tiny-ws fallback: d_o inline (correctness path)
#pragma unroll 2
                for (int j = 0; j < 32; ++j) {
                    const int d4 = j*4;
                    const float4 w3 = *(const float4*)(W1 + 3*LAT + d4);
                    const float4 w4 = *(const float4*)(W1 + 4*LAT + d4);
                    const float4 w5 = *(const float4*)(W1 + 5*LAT + d4);
                    const float4 w6 = *(const float4*)(W1 + 6*LAT + d4);
                    const float4 w7 = *(const float4*)(W1 + 7*LAT + d4);
                    const float4 w8 = *(const float4*)(W1 + 8*LAT + d4);
                    float4 dd;
                    dd.x = fmaf(px, w3.x-w6.x, fmaf(py, w4.x-w7.x, pz*(w5.x-w8.x)));
                    dd.y = fmaf(px, w3.y-w6.y, fmaf(py, w4.y-w7.y, pz*(w5.y-w8.y)));
                    dd.z = fmaf(px, w3.z-w6.z, fmaf(py, w4.z-w7.z, pz*(w5.z-w8.z)));
                    dd.w = fmaf(px, w3.w-w6.w, fmaf(py, w4.w-w7.w, pz*(w5.w-w8.w)));
                    const float4 cc = *(const float4*)(lcr + d4);
                    const float4 wd = *(const float4*)(W1 + 9*LAT + d4);
                    const float4 w2a = *(const float4*)(W2 + (d4+0)*4);
                    const float4 w2b = *(const float4*)(W2 + (d4+1)*4);
                    const float4 w2c = *(const float4*)(W2 + (d4+2)*4);
                    const float4 w2d = *(const float4*)(W2 + (d4+3)*4);
                    const float h0 = fmaxf(fmaf(wd.x, dist, cc.x + dd.x), 0.f);
                    const float h1 = fmaxf(fmaf(wd.y, dist, cc.y + dd.y), 0.f);
                    const float h2 = fmaxf(fmaf(wd.z, dist, cc.z + dd.z), 0.f);
                    const float h3 = fmaxf(fmaf(wd.w, dist, cc.w + dd.w), 0.f);
                    lg0 = fmaf(h0, w2a.x, lg0); lg1 = fmaf(h0, w2a.y, lg1);
                    lg2 = fmaf(h0, w2a.z, lg2); lg3 = fmaf(h0, w2a.w, lg3);
                    lg0 = fmaf(h1, w2b.x, lg0); lg1 = fmaf(h1, w2b.y, lg1);
                    lg2 = fmaf(h1, w2b.z, lg2); lg3 = fmaf(h1, w2b.w, lg3);
                    lg0 = fmaf(h2, w2c.x, lg0); lg1 = fmaf(h2, w2c.y, lg1);
                    lg2 = fmaf(h2, w2c.z, lg2); lg3 = fmaf(h2, w2c.w, lg3);
                    lg0 = fmaf(h3, w2d.x, lg0); lg1 = fmaf(h3, w2d.y, lg1);
                    lg2 = fmaf(h3, w2d.z, lg2); lg3 = fmaf(h3, w2d.w, lg3);
                }
            }
            // log2-domain, fold b2, mask; store qi-rotated column
            const int ocr = (i + 4*qi) & 15;
            float* lrow = lgt + (qi*4)*CHUNK + ocr;
            lrow[0*CHUNK] = mb ? fmaf(lg0, LOG2E, b2l0) : NEG_BIG;
            lrow[1*CHUNK] = mb ? fmaf(lg1, LOG2E, b2l1) : NEG_BIG;
            lrow[2*CHUNK] = mb ? fmaf(lg2, LOG2E, b2l2) : NEG_BIG;
            lrow[3*CHUNK] = mb ? fmaf(lg3, LOG2E, b2l3) : NEG_BIG;
        }
        __syncthreads();

        // ---- phase 2: softmax over obs pairs + aggregation ----
        {
            const float* rowp = lgt + (qi*4 + hstar)*CHUNK;
#pragma unroll
            for (int og = 0; og < 4; ++og) {
                const float4 t4 = *(const float4*)(rowp + ((og + qi) & 3) * 4);
#pragma unroll
                for (int pr = 0; pr < 2; ++pr) {
                    const float l0 = pr ? t4.z : t4.x;
                    const float l1 = pr ? t4.w : t4.y;
                    const float mn = fmaxf(m, fmaxf(l0, l1));
                    const float alpha = exp2f(m - mn);
                    const float p0 = (l0 > MASK_THRESH) ? exp2f(l0 - mn) : 0.f;
                    const float p1 = (l1 > MASK_THRESH) ? exp2f(l1 - mn) : 0.f;
                    lsum = fmaf(lsum, alpha, p0 + p1);
                    m = mn;

                    const float* vp = v + (size_t)(o0 + og*4 + pr*2)*LAT + d0;
                    const float4 v0A = *(const float4*)(vp);
                    const float4 v0B = *(const float4*)(vp + 4);
                    const float4 v1A = *(const float4*)(vp + LAT);
                    const float4 v1B = *(const float4*)(vp + LAT + 4);
                    accA.x = fmaf(accA.x, alpha, fmaf(p0, v0A.x, p1*v1A.x));
                    accA.y = fmaf(accA.y, alpha, fmaf(p0, v0A.y, p1*v1A.y));
                    accA.z = fmaf(accA.z, alpha, fmaf(p0, v0A.z, p1*v1A.z));
                    accA.w = fmaf(accA.w, alpha, fmaf(p0, v0A.w, p1*v1A.w));
                    accB.x = fmaf(accB.x, alpha, fmaf(p0, v0B.x, p1*v1B.x));
                    accB.y = fmaf(accB.y, alpha, fmaf(p0, v0B.y, p1*v1B.y));
                    accB.z = fmaf(accB.z, alpha, fmaf(p0, v0B.z, p1*v1B.z));
                    accB.w = fmaf(accB.w, alpha, fmaf(p0, v0B.w, p1*v1B.w));
                }
            }
        }
    }

    if (SY == 1) {
        const float inv = 1.0f / lsum;
        float* op = out + (size_t)q*LAT + d0;
        float4 rA, rB;
        rA.x = accA.x*inv; rA.y = accA.y*inv; rA.z = accA.z*inv; rA.w = accA.w*inv;
        rB.x = accB.x*inv; rB.y = accB.y*inv; rB.z = accB.z*inv; rB.w = accB.w*inv;
        *(float4*)op       = rA;
        *(float4*)(op + 4) = rB;
        return;
    }

    // ---- write partials, then split-K last-block combine ----
    {
        float* pp = ws + WS_PART + ((size_t)blockIdx.y * NQ + q) * PART_STRIDE;
        if ((i & 3) == 0) {          // one writer per head (redundant copies identical)
            pp[hstar]     = m;
            pp[4 + hstar] = lsum;
        }
        *(float4*)(pp + 8 + d0)     = accA;
        *(float4*)(pp + 8 + d0 + 4) = accB;
    }
    __syncthreads();                 // all block stores issued & drained
    if (tid == 0) {
        __threadfence();             // release: partials visible device-wide
        int* cnt = (int*)(ws + WS_CNT);
        lastflag = (atomicAdd(&cnt[blockIdx.x], 1) == SY - 1);
    }
    __syncthreads();
    if (lastflag) {
        __threadfence();             // acquire: see all other blocks' partials
        const float* base = ws + WS_PART;
        float M = NEG_BIG;
        for (int s = 0; s < SY; ++s)
            M = fmaxf(M, base[((size_t)s * NQ + q) * PART_STRIDE + hstar]);
        float Ls = 0.f;
        float4 A0 = make_float4(0.f,0.f,0.f,0.f);
        float4 A1 = make_float4(0.f,0.f,0.f,0.f);
        for (int s = 0; s < SY; ++s) {
            const float* pp = base + ((size_t)s * NQ + q) * PART_STRIDE;
            const float e = exp2f(pp[hstar] - M);
            Ls = fmaf(pp[4 + hstar], e, Ls);
            const float4 xa = *(const float4*)(pp + 8 + d0);
            const float4 xb = *(const float4*)(pp + 8 + d0 + 4);
            A0.x = fmaf(e, xa.x, A0.x); A0.y = fmaf(e, xa.y, A0.y);
            A0.z = fmaf(e, xa.z, A0.z); A0.w = fmaf(e, xa.w, A0.w);
            A1.x = fmaf(e, xb.x, A1.x); A1.y = fmaf(e, xb.y, A1.y);
            A1.z = fmaf(e, xb.z, A1.z); A1.w = fmaf(e, xb.w, A1.w);
        }
        const float inv = 1.0f / Ls;
        float* op = out + (size_t)q*LAT + d0;
        float4 rA, rB;
        rA.x = A0.x*inv; rA.y = A0.y*inv; rA.z = A0.z*inv; rA.w = A0.w*inv;
        rB.x = A1.x*inv; rB.y = A1.y*inv; rB.z = A1.z*inv; rB.w = A1.w*inv;
        *(float4*)op       = rA;
        *(float4*)(op + 4) = rB;
    }
}

// ---------------------------------------------------------------------------
extern "C" void kernel_launch(void* const* d_in, const int* in_sizes, int n_in,
                              void* d_out, int out_size, void* d_ws, size_t ws_size,
                              hipStream_t stream) {
    (void)in_sizes; (void)n_in; (void)out_size;
    float*       h_obs     = (float*)d_in[0];        // mutated in place -> v
    const float* pos_obs   = (const float*)d_in[1];
    const float* pos_query = (const float*)d_in[2];
    const int*   obs_batch = (const int*)d_in[3];
    const int*   query_batch = (const int*)d_in[4];
    const float* W1 = (const float*)d_in[5];
    const float* b1 = (const float*)d_in[6];
    const float* W2 = (const float*)d_in[7];
    const float* b2 = (const float*)d_in[8];
    const float* ln_g = (const float*)d_in[9];
    const float* ln_b = (const float*)d_in[10];
    const float* Wv = (const float*)d_in[11];
    const float* bv = (const float*)d_in[12];
    float* ws  = (float*)d_ws;
    float* out = (float*)d_out;

    // ws requirement: d_o (1 MB) + counters + SY partial slots.
    const size_t fixed = (size_t)WS_PART * sizeof(float);
    const size_t per   = (size_t)NQ * PART_STRIDE * sizeof(float);
    int SY = 1;
    float* wsf = nullptr;
    if (ws && ws_size >= fixed + 2*per) {
        size_t s = (ws_size - fixed) / per;
        SY = (int)(s < SY_MAX ? s : SY_MAX);
        wsf = ws;
    }

    gano_value<<<NO/2, 256, 0, stream>>>(ln_g, ln_b, Wv, bv, W1, pos_obs,
                                         h_obs, wsf);
    gano_main<<<dim3(NQ/16, SY), 256, 0, stream>>>(h_obs, pos_obs, pos_query,
                                                   obs_batch, query_batch,
                                                   W1, b1, W2, b2, wsf, out, SY);
}